// Round 11
// baseline (1203.237 us; speedup 1.0000x reference)
//
#include <hip/hip_runtime.h>

// Llama4TextExperts: E=8, H=2048, D=2048, 4096 tokens/expert.
// out = (up * silu(gate)) @ W2,  [gate|up] = x @ W1
// Round 11: occupancy push. 128x128 tile, BK=32, 2-deep ring (32 KiB LDS),
// 8 waves, __launch_bounds__(512,6) -> 3 blocks/CU (~75% occupancy). r8's
// pack-2-rows XOR LDS family (0-conflict verified), race-audited 2-deep
// schedule: reads; W0; BAR; stage(t+2 -> same slot); 8 MFMA; VMC2; BAR.
// Prep (cvt + W1^T + W2^T) fused in one streaming kernel before the GEMMs.

#define E_EXPERTS 8
#define TPE 4096
#define KD 2048

typedef __bf16 bf16_t;
typedef __bf16 bf16x4 __attribute__((ext_vector_type(4)));
typedef __bf16 bf16x8 __attribute__((ext_vector_type(8)));
typedef float f32x4 __attribute__((ext_vector_type(4)));

#define GLOAD16(src, dst)                                               \
  __builtin_amdgcn_global_load_lds(                                     \
      (const __attribute__((address_space(1))) void*)(src),             \
      (__attribute__((address_space(3))) void*)(dst), 16, 0, 0)

// ---------------- fused prepass: cvt + W1^T + W2^T ----------------
__device__ inline void transpose64(const float* __restrict__ Wp,
                                   bf16_t* __restrict__ Tp, int N, int K,
                                   int n0, int k0, float (*tile)[65]) {
  const int rr = threadIdx.x >> 4;        // 0..15
  const int cc = (threadIdx.x & 15) * 4;  // 0..60
#pragma unroll
  for (int p = 0; p < 4; ++p) {
    const int k = rr + p * 16;
    float4 v = *(const float4*)(Wp + (size_t)(k0 + k) * N + n0 + cc);
    tile[k][cc + 0] = v.x;
    tile[k][cc + 1] = v.y;
    tile[k][cc + 2] = v.z;
    tile[k][cc + 3] = v.w;
  }
  __syncthreads();
#pragma unroll
  for (int p = 0; p < 4; ++p) {
    const int n = rr + p * 16;
    bf16x4 o;
#pragma unroll
    for (int q = 0; q < 4; ++q) o[q] = (bf16_t)tile[cc + q][n];
    *(bf16x4*)(Tp + (size_t)(n0 + n) * K + k0 + cc) = o;
  }
}

// grid: [0,16384) = W1^T tiles; [16384,24576) = W2^T tiles; [24576,26624) cvt.
__global__ __launch_bounds__(256) void prep_kernel(
    const float* __restrict__ hs, bf16_t* __restrict__ xb,
    const float* __restrict__ w1, bf16_t* __restrict__ w1t,
    const float* __restrict__ w2, bf16_t* __restrict__ w2t) {
  __shared__ float tile[64][65];
  const int b = blockIdx.x;
  if (b < 16384) {
    const int nx = b & 63, ky = (b >> 6) & 31, e = b >> 11;
    transpose64(w1 + (size_t)e * KD * 4096, w1t + (size_t)e * 4096 * KD, 4096,
                KD, nx * 64, ky * 64, tile);
  } else if (b < 24576) {
    const int j = b - 16384;
    const int nx = j & 31, ky = (j >> 5) & 31, e = j >> 10;
    transpose64(w2 + (size_t)e * KD * KD, w2t + (size_t)e * KD * KD, KD, KD,
                nx * 64, ky * 64, tile);
  } else {
    const long n4 = (long)E_EXPERTS * TPE * KD / 4;
    long i = (long)(b - 24576) * blockDim.x + threadIdx.x;
    const long stride = 2048L * 256;
    const float4* in4 = (const float4*)hs;
    bf16x4* out4 = (bf16x4*)xb;
    for (; i < n4; i += stride) {
      float4 v = in4[i];
      bf16x4 o = {(bf16_t)v.x, (bf16_t)v.y, (bf16_t)v.z, (bf16_t)v.w};
      out4[i] = o;
    }
  }
}

// ---------------- 128x128 BK=32 3-blocks/CU grouped GEMM ----------------
// LDS: As/Bs [2 slots][64 phys rows][64 bf16]; 128 logical rows packed 2 per
// 128B phys row: row r -> phys p=r&63, half h=r>>6; chunk c in [0,8):
// k-octet kg=c&3, h=c>>2; stored at chunk c^(p&7) (involution; applied to
// stage SOURCE and to reads -> rule 21). Verified 0-conflict family (r8).
// Waves 2(M)x4(N), 64x32 per wave: A frags m0..3, B frags nf0..1.
// Per K-tile t (slot s=t&1):
//   reads(6 ds_read_b128, slot-immediate); W0; BAR;
//   stage A,B(t+2)->slot s (2 gloads/wave); 8 MFMA; VMC2; BAR.
// Audits: reads@t guarded by VMC2@t-1 (outstanding {t,t+1}->keep t+1) + BAR.
// stage(t+2)->slot s issued only after W0+BAR (all waves' slot-s reads done);
// its data first read at t+2, guarded by VMC2@t+1. Prologue: stage t0,t1;
// VMC2 (4 outstanding -> t0 landed); BAR.
template <bool FUSED, int NTN>
__global__ __launch_bounds__(512, 6) void moe_gemm128_kernel(
    const bf16_t* __restrict__ A, const bf16_t* __restrict__ Bm,
    void* __restrict__ Cout) {
  constexpr int NT = KD / 32;  // 64 K-tiles

  __shared__ alignas(16) bf16_t As[2][64][64];  // 16 KiB
  __shared__ alignas(16) bf16_t Bs[2][64][64];  // 16 KiB

  // bijective XCD swizzle (grid%8==0): one expert per XCD; intra-XCD
  // row-major (consecutive blocks share the A panel).
  const int NWG = gridDim.x;
  int wg = blockIdx.x;
  wg = (wg & 7) * (NWG >> 3) + (wg >> 3);
  const int e = wg / (32 * NTN);
  const int rem = wg % (32 * NTN);
  const int mt = rem / NTN, ntile = rem % NTN;
  const int t0 = mt * 128, n0 = ntile * 128;

  const int tid = threadIdx.x;
  const int wid = tid >> 6, lane = tid & 63;
  const int wr = wid >> 2, wc = wid & 3;  // 2(M) x 4(N); 64x32 per wave

  const bf16_t* Ae = A + (size_t)e * TPE * KD + (size_t)t0 * KD;
  const bf16_t* Be = Bm + (size_t)e * (size_t)(FUSED ? 4096 : 2048) * KD;

  // ---- staging sources (1 A-gload + 1 B-gload per wave) ----
  const int sp = lane >> 3;  // phys-row offset within the wave's 8 rows
  const int lc = lane & 7;   // written chunk

  const int pS = wid * 8 + sp;        // phys row staged by this lane
  const int cS = lc ^ (pS & 7);       // logical chunk at that position
  // A: logical row = p + 64*(c>>2); k-base = (c&3)*8
  const bf16_t* aSrc =
      Ae + (size_t)(pS + 64 * (cS >> 2)) * KD + (cS & 3) * 8;
  // B: virtual row R = n0 + p + 64*(c>>2); gate/up 16-row interleave (FUSED)
  const bf16_t* bSrc;
  {
    const int R = n0 + pS + 64 * (cS >> 2);
    int srow;
    if constexpr (FUSED)
      srow = ((R >> 5) << 4) + (R & 15) + ((R >> 4) & 1) * 2048;
    else
      srow = R;
    bSrc = Be + (size_t)srow * KD + (cS & 3) * 8;
  }

  auto stage = [&](int kt, int slot) {
    const int k0 = (kt & (NT - 1)) * 32;
    GLOAD16(aSrc + k0, &As[slot][wid * 8][0]);
    GLOAD16(bSrc + k0, &Bs[slot][wid * 8][0]);
  };

  // ---- hoisted fragment pointers (slot 0; slot adds immediate 4096 elems) ----
  const int la = lane & 15, kg4 = lane >> 4;

  const bf16_t* pA[4];
#pragma unroll
  for (int m = 0; m < 4; ++m) {
    const int r = wr * 64 + m * 16 + la;  // [0,128)
    const int p = r & 63, h = r >> 6;
    const int c = (h * 4 + kg4) ^ (p & 7);
    pA[m] = &As[0][p][c * 8];
  }
  const bf16_t* pB[2];
#pragma unroll
  for (int nf = 0; nf < 2; ++nf) {
    const int R = wc * 32 + nf * 16 + la;  // [0,128)
    const int p = R & 63, h = R >> 6;
    const int c = (h * 4 + kg4) ^ (p & 7);
    pB[nf] = &Bs[0][p][c * 8];
  }

  f32x4 acc[4][2] = {};
  bf16x8 am[4];
  bf16x8 bn[2];

#define W0 asm volatile("s_waitcnt lgkmcnt(0)" ::: "memory")
#define VMC2 asm volatile("s_waitcnt vmcnt(2)" ::: "memory")
#define BAR __builtin_amdgcn_s_barrier()
#define SCHED0 __builtin_amdgcn_sched_barrier(0)
#define PRIO1 __builtin_amdgcn_s_setprio(1)
#define PRIO0 __builtin_amdgcn_s_setprio(0)

#define TILE(t, S)                                                           \
  do {                                                                       \
    am[0] = *(const bf16x8*)(pA[0] + (S) * 4096);                            \
    am[1] = *(const bf16x8*)(pA[1] + (S) * 4096);                            \
    am[2] = *(const bf16x8*)(pA[2] + (S) * 4096);                            \
    am[3] = *(const bf16x8*)(pA[3] + (S) * 4096);                            \
    bn[0] = *(const bf16x8*)(pB[0] + (S) * 4096);                            \
    bn[1] = *(const bf16x8*)(pB[1] + (S) * 4096);                            \
    W0; SCHED0;                                                              \
    BAR;                                                                     \
    stage((t) + 2, S);                                                       \
    PRIO1;                                                                   \
    _Pragma("unroll") for (int m = 0; m < 4; ++m) {                          \
      acc[m][0] = __builtin_amdgcn_mfma_f32_16x16x32_bf16(am[m], bn[0],      \
                                                          acc[m][0], 0, 0, 0); \
      acc[m][1] = __builtin_amdgcn_mfma_f32_16x16x32_bf16(am[m], bn[1],      \
                                                          acc[m][1], 0, 0, 0); \
    }                                                                        \
    PRIO0;                                                                   \
    VMC2;                                                                    \
    BAR; SCHED0;                                                             \
  } while (0)

  // prologue: tiles 0,1 -> slots 0,1; drain tile0 (keep tile1's 2 in flight)
  stage(0, 0);
  stage(1, 1);
  VMC2;
  BAR; SCHED0;

#pragma unroll 1
  for (int t = 0; t < NT; t += 2) {
    TILE(t, 0);
    TILE(t + 1, 1);
  }

  // Epilogue. C/D layout: row=(lane>>4)*4+r, col=lane&15 (verified).
  const int rbase = t0 + wr * 64;
  if constexpr (FUSED) {
    bf16_t* Cp = (bf16_t*)Cout + (size_t)e * TPE * KD;
    const int jb = ((n0 + wc * 32) >> 1) + la;  // frag0=gate, frag1=up
#pragma unroll
    for (int m = 0; m < 4; ++m)
#pragma unroll
      for (int r = 0; r < 4; ++r) {
        const int row = rbase + m * 16 + kg4 * 4 + r;
        const float g = acc[m][0][r], u = acc[m][1][r];
        const float sg = 1.0f / (1.0f + __expf(-g));
        Cp[(size_t)row * KD + jb] = (bf16_t)(u * g * sg);
      }
  } else {
    float* Cp = (float*)Cout + (size_t)e * TPE * KD;
#pragma unroll
    for (int m = 0; m < 4; ++m)
#pragma unroll
      for (int nf = 0; nf < 2; ++nf)
#pragma unroll
        for (int r = 0; r < 4; ++r) {
          const int row = rbase + m * 16 + kg4 * 4 + r;
          const int col = n0 + wc * 32 + nf * 16 + la;
          Cp[(size_t)row * KD + col] = acc[m][nf][r];
        }
  }
#undef W0
#undef VMC2
#undef BAR
#undef SCHED0
#undef PRIO1
#undef PRIO0
#undef TILE
}

extern "C" void kernel_launch(void* const* d_in, const int* in_sizes, int n_in,
                              void* d_out, int out_size, void* d_ws,
                              size_t ws_size, hipStream_t stream) {
  const float* hs = (const float*)d_in[0];  // (32768, 2048)
  const float* w1 = (const float*)d_in[1];  // (8, 2048, 4096)
  const float* w2 = (const float*)d_in[2];  // (8, 2048, 2048)

  // ws layout (448 MiB):
  //   xb  bf16 [32768][2048]     128 MiB @ 0
  //   w1t bf16 [8][4096][2048]   128 MiB @ 128M
  //   w2t bf16 [8][2048][2048]    64 MiB @ 256M
  //   act bf16 [8][4096][2048]   128 MiB @ 320M
  char* ws = (char*)d_ws;
  bf16_t* xb = (bf16_t*)(ws);
  bf16_t* w1t = (bf16_t*)(ws + (size_t)134217728);
  bf16_t* w2t = (bf16_t*)(ws + (size_t)268435456);
  bf16_t* act = (bf16_t*)(ws + (size_t)335544320);

  // fused prepass: W1^T (16384) + W2^T (8192) + cvt (2048) = 26624 blocks
  prep_kernel<<<26624, 256, 0, stream>>>(hs, xb, w1, w1t, w2, w2t);
  // G1: virtual N=4096 -> NTN=32; grid 8*32*32 = 8192
  moe_gemm128_kernel<true, 32><<<8192, 512, 0, stream>>>(xb, w1t, (void*)act);
  // G2: N=2048 -> NTN=16; grid 8*32*16 = 4096
  moe_gemm128_kernel<false, 16><<<4096, 512, 0, stream>>>(act, w2t, d_out);
}

// Round 12
// 1094.583 us; speedup vs baseline: 1.0993x; 1.0993x over previous
//
#include <hip/hip_runtime.h>

// Llama4TextExperts: E=8, H=2048, D=2048, 4096 tokens/expert.
// out = (up * silu(gate)) @ W2,  [gate|up] = x @ W1
// Round 12: r10 base (best: 128x256, BK=32, 3-deep ring, 2 blocks/CU,
// vmcnt(3), 1 barrier/tile, fused streaming prep) + counted-lgkm TILE:
// all 8 ds_reads issued at tile start; W2 -> first 8 MFMA; W0 -> second 8.

#define E_EXPERTS 8
#define TPE 4096
#define KD 2048

typedef __bf16 bf16_t;
typedef __bf16 bf16x4 __attribute__((ext_vector_type(4)));
typedef __bf16 bf16x8 __attribute__((ext_vector_type(8)));
typedef float f32x4 __attribute__((ext_vector_type(4)));

#define GLOAD16(src, dst)                                               \
  __builtin_amdgcn_global_load_lds(                                     \
      (const __attribute__((address_space(1))) void*)(src),             \
      (__attribute__((address_space(3))) void*)(dst), 16, 0, 0)

// ---------------- fused prepass: cvt + W1^T + W2^T ----------------
__device__ inline void transpose64(const float* __restrict__ Wp,
                                   bf16_t* __restrict__ Tp, int N, int K,
                                   int n0, int k0, float (*tile)[65]) {
  const int rr = threadIdx.x >> 4;        // 0..15
  const int cc = (threadIdx.x & 15) * 4;  // 0..60
#pragma unroll
  for (int p = 0; p < 4; ++p) {
    const int k = rr + p * 16;
    float4 v = *(const float4*)(Wp + (size_t)(k0 + k) * N + n0 + cc);
    tile[k][cc + 0] = v.x;
    tile[k][cc + 1] = v.y;
    tile[k][cc + 2] = v.z;
    tile[k][cc + 3] = v.w;
  }
  __syncthreads();
#pragma unroll
  for (int p = 0; p < 4; ++p) {
    const int n = rr + p * 16;
    bf16x4 o;
#pragma unroll
    for (int q = 0; q < 4; ++q) o[q] = (bf16_t)tile[cc + q][n];
    *(bf16x4*)(Tp + (size_t)(n0 + n) * K + k0 + cc) = o;
  }
}

// grid: [0,16384) = W1^T tiles; [16384,24576) = W2^T tiles; [24576,26624) cvt.
__global__ __launch_bounds__(256) void prep_kernel(
    const float* __restrict__ hs, bf16_t* __restrict__ xb,
    const float* __restrict__ w1, bf16_t* __restrict__ w1t,
    const float* __restrict__ w2, bf16_t* __restrict__ w2t) {
  __shared__ float tile[64][65];
  const int b = blockIdx.x;
  if (b < 16384) {
    const int nx = b & 63, ky = (b >> 6) & 31, e = b >> 11;
    transpose64(w1 + (size_t)e * KD * 4096, w1t + (size_t)e * 4096 * KD, 4096,
                KD, nx * 64, ky * 64, tile);
  } else if (b < 24576) {
    const int j = b - 16384;
    const int nx = j & 31, ky = (j >> 5) & 31, e = j >> 10;
    transpose64(w2 + (size_t)e * KD * KD, w2t + (size_t)e * KD * KD, KD, KD,
                nx * 64, ky * 64, tile);
  } else {
    const long n4 = (long)E_EXPERTS * TPE * KD / 4;
    long i = (long)(b - 24576) * blockDim.x + threadIdx.x;
    const long stride = 2048L * 256;
    const float4* in4 = (const float4*)hs;
    bf16x4* out4 = (bf16x4*)xb;
    for (; i < n4; i += stride) {
      float4 v = in4[i];
      bf16x4 o = {(bf16_t)v.x, (bf16_t)v.y, (bf16_t)v.z, (bf16_t)v.w};
      out4[i] = o;
    }
  }
}

// ---------------- 128x256 BK=32 2-blocks/CU grouped GEMM ----------------
// LDS phys layout (A, 128 tile rows): phys row p in [0,64), 128B: logical
// chunk c in [0,8): half h=c>>2, k-octet kg=c&3 -> tile row p+64h, k kg*8..+8.
// Stored at chunk c^(p&7) (involution; same XOR on stage-source and read).
// B: 256 tile rows -> 128 phys rows, h = R>>7.  0-conflict verified (r8).
// Waves 2(M)x4(N), 64x64 per wave. Per K-tile t (slot s=t%3, dest s2=(s+2)%3
// = slot of t-1 whose readers drained at (t-1) W0, sealed by its BAR):
//   issue all 8 ds_reads (am x4, bn0..3) [slot-immediate]; stage t+2 (3
//   gloads); W2 (keeps bn2,bn3; DS returns in-order) -> 8 MFMA; W0 -> 8 MFMA;
//   VMC3; BAR.
// vmcnt audit: at tile end outstanding={t+1(3),t+2(3)}; VMC3 keeps t+2 -> t+1
// landed before t+1 reads (sealed by BAR).
template <bool FUSED, int NTN>
__global__ __launch_bounds__(512, 4) void moe_gemm_tlp_kernel(
    const bf16_t* __restrict__ A, const bf16_t* __restrict__ Bm,
    void* __restrict__ Cout) {
  constexpr int NT = KD / 32;  // 64 K-tiles

  __shared__ alignas(16) bf16_t As[3][64][64];    // 24 KiB
  __shared__ alignas(16) bf16_t Bs[3][128][64];   // 48 KiB

  // bijective XCD swizzle (grid%8==0): one expert per XCD; intra-XCD
  // row-major (A-panel shared by consecutive blocks).
  const int NWG = gridDim.x;
  int wg = blockIdx.x;
  wg = (wg & 7) * (NWG >> 3) + (wg >> 3);
  const int e = wg / (32 * NTN);
  const int rem = wg % (32 * NTN);
  const int mt = rem / NTN, ntile = rem % NTN;
  const int t0 = mt * 128, n0 = ntile * 256;

  const int tid = threadIdx.x;
  const int wid = tid >> 6, lane = tid & 63;
  const int wr = wid >> 2, wc = wid & 3;  // 2(M) x 4(N); 64x64 per wave

  const bf16_t* Ae = A + (size_t)e * TPE * KD + (size_t)t0 * KD;
  const bf16_t* Be = Bm + (size_t)e * (size_t)(FUSED ? 4096 : 2048) * KD;

  // ---- staging source (per-lane constants; see layout derivation above) ----
  const int sp = lane >> 3;  // phys-row offset within 8-row gload
  const int lc = lane & 7;   // written chunk

  const int pAr = wid * 8 + sp;
  const int cAr = lc ^ (pAr & 7);
  const bf16_t* aSrc = Ae + (size_t)(pAr + 64 * (cAr >> 2)) * KD + (cAr & 3) * 8;

  const bf16_t* bSrc[2];
#pragma unroll
  for (int i = 0; i < 2; ++i) {
    const int p = wid * 16 + i * 8 + sp;
    const int c = lc ^ (p & 7);
    const int R = n0 + p + 128 * (c >> 2);
    int srow;
    if constexpr (FUSED)
      srow = ((R >> 5) << 4) + (R & 15) + ((R >> 4) & 1) * 2048;
    else
      srow = R;
    bSrc[i] = Be + (size_t)srow * KD + (c & 3) * 8;
  }

  auto stageA = [&](int kt, int slot) {
    const int k0 = (kt & (NT - 1)) * 32;
    GLOAD16(aSrc + k0, &As[slot][wid * 8][0]);
  };
  auto stageB = [&](int kt, int slot) {
    const int k0 = (kt & (NT - 1)) * 32;
#pragma unroll
    for (int i = 0; i < 2; ++i)
      GLOAD16(bSrc[i] + k0, &Bs[slot][wid * 16 + i * 8][0]);
  };

  // ---- hoisted per-lane fragment addresses (slot 0; +slot immediate) ----
  const int la = lane & 15, kg4 = lane >> 4;

  const bf16_t* pA[4];
#pragma unroll
  for (int m = 0; m < 4; ++m) {
    const int r = wr * 64 + m * 16 + la;  // [0,128)
    const int p = r & 63, h = r >> 6;
    const int c = (h * 4 + kg4) ^ (p & 7);
    pA[m] = &As[0][p][c * 8];
  }
  const bf16_t* pB[4];
#pragma unroll
  for (int q = 0; q < 2; ++q)
#pragma unroll
    for (int jf = 0; jf < 2; ++jf) {
      const int R = wc * 64 + q * 32 + jf * 16 + la;  // [0,256)
      const int p = R & 127, h = R >> 7;
      const int c = (h * 4 + kg4) ^ (p & 7);
      pB[q * 2 + jf] = &Bs[0][p][c * 8];
    }

  f32x4 acc[4][4] = {};
  bf16x8 am[4];
  bf16x8 bn0, bn1, bn2, bn3;

#define W2 asm volatile("s_waitcnt lgkmcnt(2)" ::: "memory")
#define W0 asm volatile("s_waitcnt lgkmcnt(0)" ::: "memory")
#define VMC3 asm volatile("s_waitcnt vmcnt(3)" ::: "memory")
#define BAR __builtin_amdgcn_s_barrier()
#define SCHED0 __builtin_amdgcn_sched_barrier(0)
#define PRIO1 __builtin_amdgcn_s_setprio(1)
#define PRIO0 __builtin_amdgcn_s_setprio(0)

#define TILE(t, S, S2)                                                       \
  do {                                                                       \
    am[0] = *(const bf16x8*)(pA[0] + (S) * 4096);                            \
    am[1] = *(const bf16x8*)(pA[1] + (S) * 4096);                            \
    am[2] = *(const bf16x8*)(pA[2] + (S) * 4096);                            \
    am[3] = *(const bf16x8*)(pA[3] + (S) * 4096);                            \
    bn0 = *(const bf16x8*)(pB[0] + (S) * 8192);                              \
    bn1 = *(const bf16x8*)(pB[1] + (S) * 8192);                              \
    bn2 = *(const bf16x8*)(pB[2] + (S) * 8192);                              \
    bn3 = *(const bf16x8*)(pB[3] + (S) * 8192);                              \
    stageA((t) + 2, S2);                                                     \
    stageB((t) + 2, S2);                                                     \
    W2; SCHED0;                                                              \
    PRIO1;                                                                   \
    _Pragma("unroll") for (int m = 0; m < 4; ++m) {                          \
      acc[m][0] = __builtin_amdgcn_mfma_f32_16x16x32_bf16(am[m], bn0,        \
                                                          acc[m][0], 0, 0, 0); \
      acc[m][1] = __builtin_amdgcn_mfma_f32_16x16x32_bf16(am[m], bn1,        \
                                                          acc[m][1], 0, 0, 0); \
    }                                                                        \
    PRIO0;                                                                   \
    W0; SCHED0;                                                              \
    PRIO1;                                                                   \
    _Pragma("unroll") for (int m = 0; m < 4; ++m) {                          \
      acc[m][2] = __builtin_amdgcn_mfma_f32_16x16x32_bf16(am[m], bn2,        \
                                                          acc[m][2], 0, 0, 0); \
      acc[m][3] = __builtin_amdgcn_mfma_f32_16x16x32_bf16(am[m], bn3,        \
                                                          acc[m][3], 0, 0, 0); \
    }                                                                        \
    PRIO0;                                                                   \
    VMC3;                                                                    \
    BAR; SCHED0;                                                             \
  } while (0)

  // prologue: tiles 0,1 -> slots 0,1; drain tile0 (keep tile1 in flight)
  stageA(0, 0); stageB(0, 0);
  stageA(1, 1); stageB(1, 1);
  VMC3;
  BAR; SCHED0;

  int t = 0;
  for (; t < NT - 3; t += 3) {  // 21 iterations: tiles 0..62
    TILE(t, 0, 2);
    TILE(t + 1, 1, 0);
    TILE(t + 2, 2, 1);
  }
  TILE(t, 0, 2);  // tile 63 (63%3==0 -> slot 0)

  // Epilogue. C/D layout: row=(lane>>4)*4+r, col=lane&15 (verified).
  const int rbase = t0 + wr * 64;
  if constexpr (FUSED) {
    bf16_t* Cp = (bf16_t*)Cout + (size_t)e * TPE * KD;
    const int jb = (n0 >> 1) + 32 * wc;  // frag 2q=gate, 2q+1=up, same cols
#pragma unroll
    for (int m = 0; m < 4; ++m)
#pragma unroll
      for (int q = 0; q < 2; ++q)
#pragma unroll
        for (int r = 0; r < 4; ++r) {
          const int row = rbase + m * 16 + kg4 * 4 + r;
          const int col = jb + q * 16 + la;
          const float g = acc[m][2 * q][r], u = acc[m][2 * q + 1][r];
          const float sg = 1.0f / (1.0f + __expf(-g));
          Cp[(size_t)row * KD + col] = (bf16_t)(u * g * sg);
        }
  } else {
    float* Cp = (float*)Cout + (size_t)e * TPE * KD;
#pragma unroll
    for (int m = 0; m < 4; ++m)
#pragma unroll
      for (int n = 0; n < 4; ++n)
#pragma unroll
        for (int r = 0; r < 4; ++r) {
          const int row = rbase + m * 16 + kg4 * 4 + r;
          const int col = n0 + wc * 64 + n * 16 + la;
          Cp[(size_t)row * KD + col] = acc[m][n][r];
        }
  }
#undef W2
#undef W0
#undef VMC3
#undef BAR
#undef SCHED0
#undef PRIO1
#undef PRIO0
#undef TILE
}

extern "C" void kernel_launch(void* const* d_in, const int* in_sizes, int n_in,
                              void* d_out, int out_size, void* d_ws,
                              size_t ws_size, hipStream_t stream) {
  const float* hs = (const float*)d_in[0];  // (32768, 2048)
  const float* w1 = (const float*)d_in[1];  // (8, 2048, 4096)
  const float* w2 = (const float*)d_in[2];  // (8, 2048, 2048)

  // ws layout (448 MiB):
  //   xb  bf16 [32768][2048]     128 MiB @ 0
  //   w1t bf16 [8][4096][2048]   128 MiB @ 128M
  //   w2t bf16 [8][2048][2048]    64 MiB @ 256M
  //   act bf16 [8][4096][2048]   128 MiB @ 320M
  char* ws = (char*)d_ws;
  bf16_t* xb = (bf16_t*)(ws);
  bf16_t* w1t = (bf16_t*)(ws + (size_t)134217728);
  bf16_t* w2t = (bf16_t*)(ws + (size_t)268435456);
  bf16_t* act = (bf16_t*)(ws + (size_t)335544320);

  // fused prepass: W1^T (16384) + W2^T (8192) + cvt (2048) = 26624 blocks
  prep_kernel<<<26624, 256, 0, stream>>>(hs, xb, w1, w1t, w2, w2t);
  // G1: virtual N=4096 -> NTN=16; grid 8*32*16 = 4096
  moe_gemm_tlp_kernel<true, 16><<<4096, 512, 0, stream>>>(xb, w1t, (void*)act);
  // G2: N=2048 -> NTN=8; grid 8*32*8 = 2048
  moe_gemm_tlp_kernel<false, 8><<<2048, 512, 0, stream>>>(act, w2t, d_out);
}